// Round 1
// baseline (67069.592 us; speedup 1.0000x reference)
//
#include <hip/hip_runtime.h>
#include <cstdint>
#include <cstddef>

// ---------------------------------------------------------------------------
// 2-layer GRU imputation RNN (BRITS-style), B=256, T=256, D_IN=128, D_H=512.
//
// Round-0 architecture: persistent cooperative kernel, 256 workgroups x 512
// threads (one WG per CU -> all co-resident), looping over the 256 time
// steps with 3 grid-wide barriers per step (atomic counter + agent fences).
// Compute core: fp32 VALU, lanes along batch (64 batch rows per wave) so all
// activation loads/stores on the [feat][batch] workspace are coalesced and
// all weight accesses are wave-uniform (scalar-load streams).
//
// Per-step stages:
//   S1: est = H @ W_out^T + b_out ; imputed = m*x + (1-m)*est  (est-waves)
//       GH0(r,z,n) = H @ W_hh0^T + b_hh0                        (gh-waves)
//   S2: GI0 = IMP @ W_ih0^T + b_ih0 ; combine -> H1 (layer-0 GRU update)
//   S3: gates1 = H1 @ [W_ih1;W_hh1]^T ; combine -> H (layer-1, input==hidden)
// Epilogue (virtual step t==T): final est -> output_collector[:, T-1].
// ---------------------------------------------------------------------------

#define BB  256
#define TT  256
#define DIN 128
#define DH  512

// workspace layout (in floats)
#define OFF_H    64                       // barrier counter lives in ws[0]
#define OFF_H1   (OFF_H  + DH * BB)       // 131136
#define OFF_IMP  (OFF_H1 + DH * BB)       // 262208
#define OFF_GH0  (OFF_IMP + DIN * BB)     // 294976
#define WS_FLOATS (OFF_GH0 + 3 * DH * BB) // 688192 floats ~= 2.75 MB

__device__ __forceinline__ float sigm(float x) {
    return 1.0f / (1.0f + __expf(-x));
}
__device__ __forceinline__ float tanh_f(float x) {
    return 2.0f / (1.0f + __expf(-2.0f * x)) - 1.0f;
}

// Grid barrier: monotonically increasing counter, no reset (768 uses max).
// Producer side: __threadfence() (agent acq_rel -> L2 writeback) before the
// add; consumer side: __threadfence() after the spin (L1/L2 invalidate) so
// post-barrier reads see other XCDs' writes.
__device__ __forceinline__ void grid_bar(unsigned* bar, unsigned target) {
    __syncthreads();
    if (threadIdx.x == 0) {
        __threadfence();
        __hip_atomic_fetch_add(bar, 1u, __ATOMIC_RELAXED, __HIP_MEMORY_SCOPE_AGENT);
        while (__hip_atomic_load(bar, __ATOMIC_RELAXED, __HIP_MEMORY_SCOPE_AGENT) < target) {
            __builtin_amdgcn_s_sleep(4);
        }
        __threadfence();
    }
    __syncthreads();
}

__global__ __launch_bounds__(512) void rnn_kernel(
    const float* __restrict__ X,    const float* __restrict__ Mm,
    const float* __restrict__ Wih0, const float* __restrict__ Whh0,
    const float* __restrict__ bih0, const float* __restrict__ bhh0,
    const float* __restrict__ Wih1, const float* __restrict__ Whh1,
    const float* __restrict__ bih1, const float* __restrict__ bhh1,
    const float* __restrict__ Wout, const float* __restrict__ bout,
    float* __restrict__ out, float* __restrict__ ws)
{
    unsigned* bar = (unsigned*)ws;
    float* H   = ws + OFF_H;    // [DH][BB]  hidden after layer 1
    float* H1  = ws + OFF_H1;   // [DH][BB]  hidden after layer 0
    float* IMP = ws + OFF_IMP;  // [DIN][BB] imputed input
    float* GH0 = ws + OFF_GH0;  // [3][DH][BB] hidden-side gates, layer 0

    float* pre  = out;                                   // [B][T][DIN]
    float* outc = out + (size_t)BB * TT * DIN;           // [B][T][DIN]
    float* hfin = out + (size_t)2 * BB * TT * DIN;       // [B][DH]
    float* hsc  = hfin + (size_t)BB * DH;                // [B][T][DH]

    const int tid    = threadIdx.x;
    const int lane   = tid & 63;
    const int waveId = blockIdx.x * 8 + (tid >> 6);      // 0..2047

    // f-jobs (gh0 / gi0-combine / layer1): (batch-group, feature) per wave
    const int f  = __builtin_amdgcn_readfirstlane(waveId & 511);   // 0..511
    const int gW = __builtin_amdgcn_readfirstlane(waveId >> 9);    // 0..3
    const int bG = gW * 64 + lane;

    // est-jobs: waves 0..511 additionally compute est/imputed for (group, d)
    const bool hasEst = (waveId < 512);
    const int d  = __builtin_amdgcn_readfirstlane(waveId & 127);        // 0..127
    const int gE = __builtin_amdgcn_readfirstlane((waveId >> 7) & 3);   // 0..3
    const int bE = gE * 64 + lane;

    unsigned ep = 0;

    for (int t = 0; t <= TT; ++t) {
        // ------------------------- stage 1 -------------------------------
        if (hasEst) {
            float acc = bout[d];
            const float* wrow = Wout + (size_t)d * DH;
            #pragma unroll 4
            for (int k = 0; k < DH; ++k) acc += wrow[k] * H[k * BB + bE];

            if (t < TT) {
                const size_t xi = ((size_t)bE * TT + t) * DIN + d;
                const float x = X[xi];
                const float m = Mm[xi];
                const float imp = m * x + (1.0f - m) * acc;
                IMP[d * BB + bE] = imp;
                pre[xi] = acc;
                if (t > 0) outc[((size_t)bE * TT + (t - 1)) * DIN + d] = imp;
            } else {
                // final_est -> last slot of output_collector
                outc[((size_t)bE * TT + (TT - 1)) * DIN + d] = acc;
            }
        }
        if (t == TT) break;   // uniform exit; no barrier needed afterwards

        {   // gh0: rows f, f+512, f+1024 of W_hh0 against H
            float ar = bhh0[f], az = bhh0[f + DH], an = bhh0[f + 2 * DH];
            const float* wr = Whh0 + (size_t)f * DH;
            const float* wz = Whh0 + (size_t)(f + DH) * DH;
            const float* wn = Whh0 + (size_t)(f + 2 * DH) * DH;
            #pragma unroll 4
            for (int k = 0; k < DH; ++k) {
                const float h = H[k * BB + bG];
                ar += wr[k] * h; az += wz[k] * h; an += wn[k] * h;
            }
            GH0[(0 * DH + f) * BB + bG] = ar;
            GH0[(1 * DH + f) * BB + bG] = az;
            GH0[(2 * DH + f) * BB + bG] = an;
        }
        grid_bar(bar, (++ep) * 256);

        // ------------------------- stage 2 -------------------------------
        {
            float ir = bih0[f], iz = bih0[f + DH], in_ = bih0[f + 2 * DH];
            const float* wr = Wih0 + (size_t)f * DIN;
            const float* wz = Wih0 + (size_t)(f + DH) * DIN;
            const float* wn = Wih0 + (size_t)(f + 2 * DH) * DIN;
            #pragma unroll 4
            for (int k = 0; k < DIN; ++k) {
                const float v = IMP[k * BB + bG];
                ir += wr[k] * v; iz += wz[k] * v; in_ += wn[k] * v;
            }
            const float r = sigm(ir + GH0[(0 * DH + f) * BB + bG]);
            const float z = sigm(iz + GH0[(1 * DH + f) * BB + bG]);
            const float n = tanh_f(in_ + r * GH0[(2 * DH + f) * BB + bG]);
            H1[f * BB + bG] = (1.0f - z) * n + z * H[f * BB + bG];
        }
        grid_bar(bar, (++ep) * 256);

        // ------------------------- stage 3 -------------------------------
        {   // layer 1: input == hidden == H1
            float ir = bih1[f], iz = bih1[f + DH], in_ = bih1[f + 2 * DH];
            float hr = bhh1[f], hz = bhh1[f + DH], hn = bhh1[f + 2 * DH];
            const float* air = Wih1 + (size_t)f * DH;
            const float* aiz = Wih1 + (size_t)(f + DH) * DH;
            const float* ain = Wih1 + (size_t)(f + 2 * DH) * DH;
            const float* ahr = Whh1 + (size_t)f * DH;
            const float* ahz = Whh1 + (size_t)(f + DH) * DH;
            const float* ahn = Whh1 + (size_t)(f + 2 * DH) * DH;
            #pragma unroll 2
            for (int k = 0; k < DH; ++k) {
                const float v = H1[k * BB + bG];
                ir += air[k] * v; iz += aiz[k] * v; in_ += ain[k] * v;
                hr += ahr[k] * v; hz += ahz[k] * v; hn += ahn[k] * v;
            }
            const float r = sigm(ir + hr);
            const float z = sigm(iz + hz);
            const float n = tanh_f(in_ + r * hn);
            const float hnew = (1.0f - z) * n + z * H1[f * BB + bG];
            H[f * BB + bG] = hnew;
            hsc[((size_t)bG * TT + t) * DH + f] = hnew;
            if (t == TT - 1) hfin[(size_t)bG * DH + f] = hnew;
        }
        grid_bar(bar, (++ep) * 256);
    }
}

extern "C" void kernel_launch(void* const* d_in, const int* in_sizes, int n_in,
                              void* d_out, int out_size, void* d_ws, size_t ws_size,
                              hipStream_t stream) {
    const float* X    = (const float*)d_in[0];
    const float* Mm   = (const float*)d_in[1];
    const float* Wih0 = (const float*)d_in[2];
    const float* Whh0 = (const float*)d_in[3];
    const float* bih0 = (const float*)d_in[4];
    const float* bhh0 = (const float*)d_in[5];
    const float* Wih1 = (const float*)d_in[6];
    const float* Whh1 = (const float*)d_in[7];
    const float* bih1 = (const float*)d_in[8];
    const float* bhh1 = (const float*)d_in[9];
    const float* Wout = (const float*)d_in[10];
    const float* bout = (const float*)d_in[11];
    float* out = (float*)d_out;
    float* ws  = (float*)d_ws;

    // zero the barrier counter + initial hidden state H (rest of ws is
    // written before it is read)
    hipMemsetAsync(d_ws, 0, (size_t)(OFF_H + DH * BB) * sizeof(float), stream);

    // grid == 256 workgroups <= 256 CUs with a 512-thread block -> all WGs
    // co-resident; the in-kernel atomic barrier is safe.
    hipLaunchKernelGGL(rnn_kernel, dim3(256), dim3(512), 0, stream,
                       X, Mm, Wih0, Whh0, bih0, bhh0,
                       Wih1, Whh1, bih1, bhh1, Wout, bout, out, ws);
}

// Round 2
// 17064.832 us; speedup vs baseline: 3.9303x; 3.9303x over previous
//
#include <hip/hip_runtime.h>
#include <cstdint>
#include <cstddef>

// ---------------------------------------------------------------------------
// 2-layer GRU imputation RNN, B=256, T=256, D_IN=128, D_H=512.
// R1: persistent cooperative kernel + MFMA bf16 (16x16x32), LDS-staged A-tiles,
// fp32 carried state for the elementwise combine. 256 WGs x 512 thr (8 waves),
// WG = (batch-block bb of 16, feature-group fg of 16). 3 grid barriers/step.
// ---------------------------------------------------------------------------

#define BB  256
#define TT  256
#define DIN 128
#define DH  512

typedef __attribute__((ext_vector_type(8))) short short8;   // 8 x bf16
typedef __attribute__((ext_vector_type(4))) float f32x4;
typedef unsigned short u16;

// ws layout (float units)
#define OFF_BAR   0
#define OFF_H32   64                              // [256][512] f32 (carried h, exact)
#define OFF_HBF   (OFF_H32 + BB*DH)               // [256][512] bf16
#define OFF_H132  (OFF_HBF + BB*DH/2)             // [256][512] f32 (layer-0 out)
#define OFF_H1BF  (OFF_H132 + BB*DH)              // [256][512] bf16
#define OFF_IMPBF (OFF_H1BF + BB*DH/2)            // [256][128] bf16
#define OFF_GH0   (OFF_IMPBF + BB*DIN/2)          // [3][256][512] f32 (incl. b_hh0)
#define OFF_WOUT  (OFF_GH0 + 3*BB*DH)             // bf16 weights below
#define OFF_WHH0  (OFF_WOUT + (DIN*DH)/2)
#define OFF_WIH0  (OFF_WHH0 + (3*DH*DH)/2)
#define OFF_WIH1  (OFF_WIH0 + (3*DH*DIN)/2)
#define OFF_WHH1  (OFF_WIH1 + (3*DH*DH)/2)
#define WS_FLOATS (OFF_WHH1 + (3*DH*DH)/2)        // 2,048,064 floats ~ 8.2 MB

__device__ __forceinline__ float sigm(float x)   { return 1.0f / (1.0f + __expf(-x)); }
__device__ __forceinline__ float tanh_f(float x) { return 2.0f / (1.0f + __expf(-2.0f * x)) - 1.0f; }

__device__ __forceinline__ u16 f2bf(float x) {            // RNE f32->bf16
    unsigned u = __builtin_bit_cast(unsigned, x);
    u += 0x7fffu + ((u >> 16) & 1u);
    return (u16)(u >> 16);
}

__device__ __forceinline__ void grid_bar(unsigned* bar, unsigned target) {
    __syncthreads();
    if (threadIdx.x == 0) {
        __threadfence();
        __hip_atomic_fetch_add(bar, 1u, __ATOMIC_RELAXED, __HIP_MEMORY_SCOPE_AGENT);
        while (__hip_atomic_load(bar, __ATOMIC_RELAXED, __HIP_MEMORY_SCOPE_AGENT) < target) {
            __builtin_amdgcn_s_sleep(1);
        }
        __threadfence();
    }
    __syncthreads();
}

// fp32 -> bf16 weight conversion (runs once per call, before the RNN kernel)
__global__ void prep_kernel(const float* __restrict__ Wout, const float* __restrict__ Whh0,
                            const float* __restrict__ Wih0, const float* __restrict__ Wih1,
                            const float* __restrict__ Whh1, float* __restrict__ ws) {
    u16* dOut = (u16*)(ws + OFF_WOUT);
    u16* dHH0 = (u16*)(ws + OFF_WHH0);
    u16* dIH0 = (u16*)(ws + OFF_WIH0);
    u16* dIH1 = (u16*)(ws + OFF_WIH1);
    u16* dHH1 = (u16*)(ws + OFF_WHH1);
    const int N0 = DIN * DH, N1 = 3 * DH * DH, N2 = 3 * DH * DIN;
    const int total = N0 + 3 * N1 + N2;
    for (int i = blockIdx.x * 256 + threadIdx.x; i < total; i += gridDim.x * 256) {
        int j = i;
        if (j < N0) { dOut[j] = f2bf(Wout[j]); continue; } j -= N0;
        if (j < N1) { dHH0[j] = f2bf(Whh0[j]); continue; } j -= N1;
        if (j < N2) { dIH0[j] = f2bf(Wih0[j]); continue; } j -= N2;
        if (j < N1) { dIH1[j] = f2bf(Wih1[j]); continue; } j -= N1;
        dHH1[j] = f2bf(Whh1[j]);
    }
}

__global__ __launch_bounds__(512) void rnn_kernel(
    const float* __restrict__ X,    const float* __restrict__ Mm,
    const float* __restrict__ bih0, const float* __restrict__ bhh0,
    const float* __restrict__ bih1, const float* __restrict__ bhh1,
    const float* __restrict__ bout,
    float* __restrict__ out, float* __restrict__ ws)
{
    __shared__ __align__(16) u16 Atile[16 * 520];    // A-tile, padded rows (16B)
    __shared__ float cplane[2][3][256];              // stage-3 combine exchange

    unsigned* bar = (unsigned*)(ws + OFF_BAR);
    float* H32  = ws + OFF_H32;
    u16*   Hbf  = (u16*)(ws + OFF_HBF);
    float* H132 = ws + OFF_H132;
    u16*   H1bf = (u16*)(ws + OFF_H1BF);
    u16*   IMPbf= (u16*)(ws + OFF_IMPBF);
    float* GH0  = ws + OFF_GH0;
    const u16* WbOut = (const u16*)(ws + OFF_WOUT);
    const u16* WbHH0 = (const u16*)(ws + OFF_WHH0);
    const u16* WbIH0 = (const u16*)(ws + OFF_WIH0);
    const u16* WbIH1 = (const u16*)(ws + OFF_WIH1);
    const u16* WbHH1 = (const u16*)(ws + OFF_WHH1);

    float* pre  = out;                               // [B][T][DIN]
    float* outc = out + BB * TT * DIN;               // [B][T][DIN]
    float* hfin = out + 2 * BB * TT * DIN;           // [B][DH]
    float* hsc  = hfin + BB * DH;                    // [B][T][DH]

    const int tid  = threadIdx.x;
    const int lane = tid & 63;
    const int v    = tid >> 6;           // wave 0..7
    const int bb   = blockIdx.x & 15;    // batch block (16 rows)
    const int fg   = blockIdx.x >> 4;    // feature group
    const int m_   = lane & 15;          // A-row / B-col / C-col index
    const int q    = lane >> 4;          // quad
    const int q8   = q * 8;
    const int rowB = bb * 16 + q * 4;    // C-row batch base (+r)

    unsigned ep = 0;

    for (int t = 0; t <= TT; ++t) {
        // ---------------- stage 1: A = H_prev (16 x 512) ----------------
        {
            const u16* src = Hbf + bb * 16 * DH;
            for (int ch = tid; ch < 1024; ch += 512) {
                const int r = ch >> 6, c = ch & 63;
                *(uint4*)(Atile + r * 520 + (c << 3)) = *(const uint4*)(src + r * DH + (c << 3));
            }
        }
        __syncthreads();

        const int ftile = fg + 16 * v;
        if (v < 7 && ftile < 104 && (t < TT || ftile < 8)) {
            const bool isEst = ftile < 8;
            const int f0 = (isEst ? ftile : (ftile - 8)) * 16;
            const u16* Bw = (isEst ? WbOut : WbHH0) + (size_t)(f0 + m_) * DH;
            f32x4 acc = {0.f, 0.f, 0.f, 0.f};
            #pragma unroll 4
            for (int kb = 0; kb < DH; kb += 32) {
                short8 a  = *(const short8*)(Atile + m_ * 520 + kb + q8);
                short8 b8 = *(const short8*)(Bw + kb + q8);
                acc = __builtin_amdgcn_mfma_f32_16x16x32_bf16(a, b8, acc, 0, 0, 0);
            }
            if (isEst) {
                const int f = f0 + m_;
                const float bo = bout[f];
                #pragma unroll
                for (int r = 0; r < 4; ++r) {
                    const int b = rowB + r;
                    const float est = acc[r] + bo;
                    if (t < TT) {
                        const int xi = (b * TT + t) * DIN + f;
                        const float x = X[xi], mm = Mm[xi];
                        const float imp = mm * x + (1.f - mm) * est;
                        IMPbf[b * DIN + f] = f2bf(imp);
                        pre[xi] = est;
                        if (t > 0) outc[(b * TT + t - 1) * DIN + f] = imp;
                    } else {
                        outc[(b * TT + TT - 1) * DIN + f] = est;   // final est
                    }
                }
            } else {
                const int fp = f0 + m_;                  // 0..1535
                const int g = fp >> 9, ff = fp & 511;
                const float bh = bhh0[fp];
                float* dst = GH0 + (size_t)g * BB * DH + ff;
                #pragma unroll
                for (int r = 0; r < 4; ++r)
                    dst[(size_t)(rowB + r) * DH] = acc[r] + bh;
            }
        }
        if (t == TT) break;              // uniform exit
        grid_bar(bar, (++ep) * 256);

        // ---------------- stage 2: A = IMP (16 x 128) -------------------
        {
            const u16* src = IMPbf + bb * 16 * DIN;
            for (int ch = tid; ch < 256; ch += 512) {
                const int r = ch >> 4, c = ch & 15;
                *(uint4*)(Atile + r * 136 + (c << 3)) = *(const uint4*)(src + r * DIN + (c << 3));
            }
        }
        __syncthreads();

        if (v < 2) {
            const int ff0 = (fg + 16 * v) * 16;
            const u16* B0 = WbIH0 + (size_t)(ff0 + m_) * DIN;
            const u16* B1 = B0 + (size_t)DH * DIN;
            const u16* B2 = B1 + (size_t)DH * DIN;
            f32x4 a0 = {0.f,0.f,0.f,0.f}, a1 = a0, a2 = a0;
            #pragma unroll
            for (int kb = 0; kb < DIN; kb += 32) {
                short8 a = *(const short8*)(Atile + m_ * 136 + kb + q8);
                a0 = __builtin_amdgcn_mfma_f32_16x16x32_bf16(a, *(const short8*)(B0 + kb + q8), a0, 0, 0, 0);
                a1 = __builtin_amdgcn_mfma_f32_16x16x32_bf16(a, *(const short8*)(B1 + kb + q8), a1, 0, 0, 0);
                a2 = __builtin_amdgcn_mfma_f32_16x16x32_bf16(a, *(const short8*)(B2 + kb + q8), a2, 0, 0, 0);
            }
            const int ff = ff0 + m_;
            const float bi0 = bih0[ff], bi1 = bih0[DH + ff], bi2 = bih0[2 * DH + ff];
            #pragma unroll
            for (int r = 0; r < 4; ++r) {
                const int b = rowB + r;
                const float ghr = GH0[(size_t)b * DH + ff];
                const float ghz = GH0[((size_t)BB + b) * DH + ff];
                const float ghn = GH0[((size_t)2 * BB + b) * DH + ff];
                const float rr = sigm(a0[r] + bi0 + ghr);
                const float zz = sigm(a1[r] + bi1 + ghz);
                const float nn = tanh_f(a2[r] + bi2 + rr * ghn);
                const float hp = H32[(size_t)b * DH + ff];
                const float h1 = (1.f - zz) * nn + zz * hp;
                H132[(size_t)b * DH + ff] = h1;
                H1bf[b * DH + ff] = f2bf(h1);
            }
        }
        grid_bar(bar, (++ep) * 256);

        // ---------------- stage 3: A = H1 (16 x 512) --------------------
        {
            const u16* src = H1bf + bb * 16 * DH;
            for (int ch = tid; ch < 1024; ch += 512) {
                const int r = ch >> 6, c = ch & 63;
                *(uint4*)(Atile + r * 520 + (c << 3)) = *(const uint4*)(src + r * DH + (c << 3));
            }
        }
        __syncthreads();

        float sr[4];                                   // gate-r preact (g==0 waves)
        if (v < 6) {
            const int ft = (v < 3) ? 0 : 1;
            const int g  = v - 3 * ft;
            const int ff0 = (fg + 16 * ft) * 16;
            const u16* Bi = WbIH1 + (size_t)(g * DH + ff0 + m_) * DH;
            const u16* Bh = WbHH1 + (size_t)(g * DH + ff0 + m_) * DH;
            f32x4 ai = {0.f,0.f,0.f,0.f}, ah = ai;
            #pragma unroll 4
            for (int kb = 0; kb < DH; kb += 32) {
                short8 a = *(const short8*)(Atile + m_ * 520 + kb + q8);
                ai = __builtin_amdgcn_mfma_f32_16x16x32_bf16(a, *(const short8*)(Bi + kb + q8), ai, 0, 0, 0);
                ah = __builtin_amdgcn_mfma_f32_16x16x32_bf16(a, *(const short8*)(Bh + kb + q8), ah, 0, 0, 0);
            }
            const int gf = g * DH + ff0 + m_;
            const float bi = bih1[gf], bh = bhh1[gf];
            if (g == 0) {
                #pragma unroll
                for (int r = 0; r < 4; ++r) sr[r] = ai[r] + ah[r] + bi + bh;
            } else if (g == 1) {
                #pragma unroll
                for (int r = 0; r < 4; ++r) cplane[ft][0][m_ * 16 + q * 4 + r] = ai[r] + ah[r] + bi + bh;
            } else {
                #pragma unroll
                for (int r = 0; r < 4; ++r) {
                    cplane[ft][1][m_ * 16 + q * 4 + r] = ai[r] + bi;   // in_
                    cplane[ft][2][m_ * 16 + q * 4 + r] = ah[r] + bh;   // hn
                }
            }
        }
        __syncthreads();
        if (v == 0 || v == 3) {
            const int ft = v / 3;
            const int ff = (fg + 16 * ft) * 16 + m_;
            #pragma unroll
            for (int r = 0; r < 4; ++r) {
                const int b = rowB + r;
                const int idx = m_ * 16 + q * 4 + r;
                const float rr = sigm(sr[r]);
                const float zz = sigm(cplane[ft][0][idx]);
                const float nn = tanh_f(cplane[ft][1][idx] + rr * cplane[ft][2][idx]);
                const float h1 = H132[(size_t)b * DH + ff];
                const float hn = (1.f - zz) * nn + zz * h1;
                H32[(size_t)b * DH + ff] = hn;
                Hbf[b * DH + ff] = f2bf(hn);
                hsc[((size_t)b * TT + t) * DH + ff] = hn;
                if (t == TT - 1) hfin[(size_t)b * DH + ff] = hn;
            }
        }
        grid_bar(bar, (++ep) * 256);
    }
}

extern "C" void kernel_launch(void* const* d_in, const int* in_sizes, int n_in,
                              void* d_out, int out_size, void* d_ws, size_t ws_size,
                              hipStream_t stream) {
    const float* X    = (const float*)d_in[0];
    const float* Mm   = (const float*)d_in[1];
    const float* Wih0 = (const float*)d_in[2];
    const float* Whh0 = (const float*)d_in[3];
    const float* bih0 = (const float*)d_in[4];
    const float* bhh0 = (const float*)d_in[5];
    const float* Wih1 = (const float*)d_in[6];
    const float* Whh1 = (const float*)d_in[7];
    const float* bih1 = (const float*)d_in[8];
    const float* bhh1 = (const float*)d_in[9];
    const float* Wout = (const float*)d_in[10];
    const float* bout = (const float*)d_in[11];
    float* out = (float*)d_out;
    float* ws  = (float*)d_ws;

    // zero barrier counter + H32 + Hbf (initial hidden state)
    hipMemsetAsync(d_ws, 0, (size_t)(OFF_H132) * sizeof(float), stream);

    // weights fp32 -> bf16
    hipLaunchKernelGGL(prep_kernel, dim3(1024), dim3(256), 0, stream,
                       Wout, Whh0, Wih0, Wih1, Whh1, ws);

    // persistent RNN: 256 WGs (<= 256 CUs) x 512 threads, co-resident
    hipLaunchKernelGGL(rnn_kernel, dim3(256), dim3(512), 0, stream,
                       X, Mm, bih0, bhh0, bih1, bhh1, bout, out, ws);
}